// Round 6
// baseline (2479.108 us; speedup 1.0000x reference)
//
#include <hip/hip_runtime.h>
#include <math.h>

#define TINYF 1.17549435e-38f
#define NCHUNK 25
#define CHUNKJ 2000
#define QCAP 2048
#define GMAX 16.0f   // hard upper bound on gumbel (15.9424) + slack

// ---------------- threefry2x32, key = (0, 42), partitionable xor-combine ----
__device__ __forceinline__ unsigned rotl32(unsigned x, int r) {
  return (x << r) | (x >> (32 - r));
}

__device__ __forceinline__ unsigned tf2x32_xor(unsigned x0, unsigned x1) {
  const unsigned k0 = 0u, k1 = 42u, k2 = 0x1BD11BF0u;  // 0x1BD11BDA ^ 0 ^ 42
  x0 += k0; x1 += k1;
#define TFR(r) { x0 += x1; x1 = rotl32(x1, r); x1 ^= x0; }
  TFR(13) TFR(15) TFR(26) TFR(6)
  x0 += k1; x1 += k2 + 1u;
  TFR(17) TFR(29) TFR(16) TFR(24)
  x0 += k2; x1 += k0 + 2u;
  TFR(13) TFR(15) TFR(26) TFR(6)
  x0 += k0; x1 += k1 + 3u;
  TFR(17) TFR(29) TFR(16) TFR(24)
  x0 += k1; x1 += k2 + 4u;
  TFR(13) TFR(15) TFR(26) TFR(6)
  x0 += k2; x1 += k0 + 5u;
#undef TFR
  return x0 ^ x1;
}

__device__ __forceinline__ float gumbel_from_bits(unsigned bits) {
  float f = __uint_as_float((bits >> 9) | 0x3f800000u) - 1.0f;
  float u = fmaxf(f, TINYF);
  return -logf(-logf(u));
}

// order-preserving float->uint (monotone)
__device__ __forceinline__ unsigned ordf(float v) {
  unsigned b = __float_as_uint(v);
  return (b & 0x80000000u) ? ~b : (b | 0x80000000u);
}
__device__ __forceinline__ float unordf(unsigned u) {
  unsigned b = (u & 0x80000000u) ? (u & 0x7FFFFFFFu) : ~u;
  return __uint_as_float(b);
}

// ---------------- h = x @ W + b (f64 accumulate) ----------------
__global__ void k_hraw(const float* __restrict__ x, const float* __restrict__ W,
                       const float* __restrict__ b, float* __restrict__ hraw) {
  __shared__ float sx[256];
  const int i = blockIdx.x;
  const int d = threadIdx.x;  // 128 threads
  sx[d] = x[i * 256 + d];
  sx[d + 128] = x[i * 256 + 128 + d];
  __syncthreads();
  double acc = 0.0;
  for (int k = 0; k < 256; ++k)
    acc = fma((double)sx[k], (double)W[k * 128 + d], acc);
  hraw[i * 128 + d] = (float)acc + b[d];
}

// ---------------- BN stats per column (f64) ----------------
__global__ void k_bnstats(const float* __restrict__ hraw,
                          float* __restrict__ meanv, float* __restrict__ rsv) {
  __shared__ double red[256];
  const int d = blockIdx.x;   // 128 blocks
  const int t = threadIdx.x;  // 256 threads
  double s = 0.0;
  for (int i = t; i < 2048; i += 256) s += (double)hraw[i * 128 + d];
  red[t] = s;
  __syncthreads();
  for (int off = 128; off > 0; off >>= 1) {
    if (t < off) red[t] += red[t + off];
    __syncthreads();
  }
  const float m = (float)(red[0] * (1.0 / 2048.0));
  __syncthreads();
  double v = 0.0;
  for (int i = t; i < 2048; i += 256) {
    float dd = __fsub_rn(hraw[i * 128 + d], m);
    v += (double)dd * (double)dd;
  }
  red[t] = v;
  __syncthreads();
  for (int off = 128; off > 0; off >>= 1) {
    if (t < off) red[t] += red[t + off];
    __syncthreads();
  }
  if (t == 0) {
    float var = (float)(red[0] * (1.0 / 2048.0));
    float vpe = __fadd_rn(var, 1e-5f);
    meanv[d] = m;
    rsv[d] = (float)(1.0 / sqrt((double)vpe));
  }
}

// ---------------- apply BN + leaky relu ----------------
__global__ void k_apply(const float* __restrict__ hraw,
                        const float* __restrict__ meanv, const float* __restrict__ rsv,
                        const float* __restrict__ gamma, const float* __restrict__ beta,
                        float* __restrict__ hfin) {
  const int idx = blockIdx.x * 256 + threadIdx.x;
  const int d = idx & 127;
  float h = hraw[idx];
  float hn = __fadd_rn(__fmul_rn(__fmul_rn(__fsub_rn(h, meanv[d]), rsv[d]), gamma[d]), beta[d]);
  hfin[idx] = (hn >= 0.0f) ? hn : __fmul_rn(0.01f, hn);
}

// ---------------- V0 seed: per-row achieved max over j in [0,1024) ----------
__global__ __launch_bounds__(256, 4) void k_seed(const float* __restrict__ hfin,
                                                 const float* __restrict__ items,
                                                 float* __restrict__ V0) {
  __shared__ float red[4][256];
  const int t = threadIdx.x;
  const int rbase = blockIdx.x * 4;
  float best[4] = {-INFINITY, -INFINITY, -INFINITY, -INFINITY};
  for (int q = 0; q < 4; ++q) {
    const int j = t + 256 * q;
    float acc[4] = {0.0f, 0.0f, 0.0f, 0.0f};
    const float* ap = items + (size_t)j * 128;
    for (int km = 0; km < 8; ++km) {
#pragma unroll
      for (int e = 0; e < 4; ++e) {
        float4 a4 = *(const float4*)(ap + km * 16 + 4 * e);
        float4 h4[4];
#pragma unroll
        for (int p = 0; p < 4; ++p)
          h4[p] = *(const float4*)(hfin + (rbase + p) * 128 + km * 16 + 4 * e);
#pragma unroll
        for (int p = 0; p < 4; ++p) {
          acc[p] = fmaf(h4[p].x, a4.x, acc[p]);
          acc[p] = fmaf(h4[p].y, a4.y, acc[p]);
          acc[p] = fmaf(h4[p].z, a4.z, acc[p]);
          acc[p] = fmaf(h4[p].w, a4.w, acc[p]);
        }
      }
    }
#pragma unroll
    for (int p = 0; p < 4; ++p) {
      unsigned l = (unsigned)(rbase + p) * 50000u + (unsigned)j;
      float g = gumbel_from_bits(tf2x32_xor(0u, l));
      best[p] = fmaxf(best[p], acc[p] + g);
    }
  }
#pragma unroll
  for (int p = 0; p < 4; ++p) red[p][t] = best[p];
  __syncthreads();
  for (int off = 128; off > 0; off >>= 1) {
    if (t < off) {
#pragma unroll
      for (int p = 0; p < 4; ++p) red[p][t] = fmaxf(red[p][t], red[p][t + off]);
    }
    __syncthreads();
  }
  if (t < 4) V0[rbase + t] = red[t][0];
}

// ---------------- fused scores + pruned gumbel + argmax ----------------
// grid 3200: bid -> rowtile rt = bid/25 (rows rt*16..+15), chunk c = bid%25
// (j in [c*2000,(c+1)*2000)). Per thread: 4 j-columns (t, t+256, t+512, t+768)
// x 16 rows. Loads explicitly batched (4 a-float4 + 8 h-float4 in flight) so
// L1/L2 latency amortizes ~8x; T_j=4 halves broadcast-h traffic per FMA.
__global__ __launch_bounds__(256, 4) void k_scores(const float* __restrict__ hfin,
                                                   const float* __restrict__ items,
                                                   const float* __restrict__ V0,
                                                   float* __restrict__ pmax,
                                                   int* __restrict__ pidx) {
  __shared__ unsigned q_key[QCAP];
  __shared__ float q_val[QCAP];
  __shared__ unsigned long long rowslot[16];
  __shared__ unsigned q_cnt;

  const int t = threadIdx.x;
  const int bid = blockIdx.x;
  const int rt = bid / 25;
  const int c = bid - rt * 25;
  const int r0 = rt * 16;
  const int jlo = c * CHUNKJ;
  const int jhi = jlo + CHUNKJ;
  const float* hbase = hfin + r0 * 128;

  if (t == 0) q_cnt = 0;
  if (t < 16) rowslot[t] = 0ull;
  __syncthreads();

  for (int jt = 0; jt < 2; ++jt) {
    int jj[4];
    bool vj[4];
    const float* ap[4];
#pragma unroll
    for (int u = 0; u < 4; ++u) {
      jj[u] = jlo + jt * 1024 + t + 256 * u;
      vj[u] = jj[u] < jhi;
      int jc = vj[u] ? jj[u] : (jhi - 1);
      ap[u] = items + (size_t)jc * 128;
    }

    float acc[4][16];
#pragma unroll
    for (int u = 0; u < 4; ++u)
#pragma unroll
      for (int p = 0; p < 16; ++p) acc[u][p] = 0.0f;

    for (int km = 0; km < 8; ++km) {
#pragma unroll
      for (int e = 0; e < 4; ++e) {
        const int ko = km * 16 + 4 * e;
        float4 a4[4];
#pragma unroll
        for (int u = 0; u < 4; ++u) a4[u] = *(const float4*)(ap[u] + ko);

        // phase 1: rows 0..7 batched
        {
          float4 h4[8];
#pragma unroll
          for (int p = 0; p < 8; ++p)
            h4[p] = *(const float4*)(hbase + p * 128 + ko);
#pragma unroll
          for (int p = 0; p < 8; ++p)
#pragma unroll
            for (int u = 0; u < 4; ++u) {
              acc[u][p] = fmaf(h4[p].x, a4[u].x, acc[u][p]);
              acc[u][p] = fmaf(h4[p].y, a4[u].y, acc[u][p]);
              acc[u][p] = fmaf(h4[p].z, a4[u].z, acc[u][p]);
              acc[u][p] = fmaf(h4[p].w, a4[u].w, acc[u][p]);
            }
        }
        // phase 2: rows 8..15 batched
        {
          float4 h4[8];
#pragma unroll
          for (int p = 0; p < 8; ++p)
            h4[p] = *(const float4*)(hbase + (p + 8) * 128 + ko);
#pragma unroll
          for (int p = 0; p < 8; ++p)
#pragma unroll
            for (int u = 0; u < 4; ++u) {
              acc[u][p + 8] = fmaf(h4[p].x, a4[u].x, acc[u][p + 8]);
              acc[u][p + 8] = fmaf(h4[p].y, a4[u].y, acc[u][p + 8]);
              acc[u][p + 8] = fmaf(h4[p].z, a4[u].z, acc[u][p + 8]);
              acc[u][p + 8] = fmaf(h4[p].w, a4[u].w, acc[u][p + 8]);
            }
        }
      }
    }

    // push candidates: keep iff s + GMAX >= V0[row]
#pragma unroll
    for (int p = 0; p < 16; ++p) {
      const float vth = V0[r0 + p] - GMAX;  // uniform
#pragma unroll
      for (int u = 0; u < 4; ++u) {
        if (vj[u] && acc[u][p] >= vth) {
          unsigned slot = atomicAdd(&q_cnt, 1u);
          if (slot < QCAP) {
            q_key[slot] = ((unsigned)p << 16) | (unsigned)jj[u];
            q_val[slot] = acc[u][p];
          } else {  // overflow fallback: inline
            unsigned l = (unsigned)(r0 + p) * 50000u + (unsigned)jj[u];
            float v = acc[u][p] + gumbel_from_bits(tf2x32_xor(0u, l));
            unsigned long long pk =
                ((unsigned long long)ordf(v) << 32) | (0xFFFFFFFFu - (unsigned)jj[u]);
            atomicMax(&rowslot[p], pk);
          }
        }
      }
    }
  }

  __syncthreads();
  // dense flush: compute gumbel only for candidates
  const unsigned n = (q_cnt < QCAP) ? q_cnt : QCAP;
  for (unsigned i = t; i < n; i += 256) {
    unsigned key = q_key[i];
    unsigned p = key >> 16;
    unsigned j = key & 0xFFFFu;
    float s = q_val[i];
    unsigned l = (r0 + p) * 50000u + j;
    float v = s + gumbel_from_bits(tf2x32_xor(0u, l));
    unsigned long long pk = ((unsigned long long)ordf(v) << 32) | (0xFFFFFFFFu - j);
    atomicMax(&rowslot[p], pk);
  }
  __syncthreads();

  if (t < 16) {
    unsigned long long pk = rowslot[t];
    if (pk == 0ull) {
      pmax[(r0 + t) * NCHUNK + c] = -INFINITY;
      pidx[(r0 + t) * NCHUNK + c] = 0;
    } else {
      pmax[(r0 + t) * NCHUNK + c] = unordf((unsigned)(pk >> 32));
      pidx[(r0 + t) * NCHUNK + c] = (int)(0xFFFFFFFFu - (unsigned)pk);
    }
  }
}

// ---------------- chunk merge + cosine sim (one wave per row) ----------------
__global__ void k_final(const float* __restrict__ pmax, const int* __restrict__ pidx,
                        const int* __restrict__ uid, const float* __restrict__ items,
                        float* __restrict__ dout, float* __restrict__ simv) {
  const int r = blockIdx.x;
  const int lane = threadIdx.x;  // 64
  float bm = -INFINITY;
  int bi = 0;
  for (int c = 0; c < NCHUNK; ++c) {  // ascending c = ascending j
    float v = pmax[r * NCHUNK + c];
    int id = pidx[r * NCHUNK + c];
    if (v > bm || (v == bm && id < bi)) { bm = v; bi = id; }
  }
  if (lane == 0) dout[r] = (float)bi;

  const int orig = uid[r * 2 + 1];
  float o1 = items[(size_t)orig * 128 + lane];
  float o2 = items[(size_t)orig * 128 + 64 + lane];
  float p1 = items[(size_t)bi * 128 + lane];
  float p2 = items[(size_t)bi * 128 + 64 + lane];
  float d = o1 * p1 + o2 * p2;
  float s1 = o1 * o1 + o2 * o2;
  float s2 = p1 * p1 + p2 * p2;
  for (int off = 32; off > 0; off >>= 1) {
    d += __shfl_down(d, off);
    s1 += __shfl_down(s1, off);
    s2 += __shfl_down(s2, off);
  }
  if (lane == 0) {
    float n1 = fmaxf(sqrtf(s1), 1e-6f);
    float n2 = fmaxf(sqrtf(s2), 1e-6f);
    float sim = d / (n1 * n2);
    simv[r] = (sim + 1.0f) * 0.5f;
  }
}

// ---------------- final scalar reductions ----------------
__global__ void k_reduce(const float* __restrict__ simv, float* __restrict__ dout) {
  __shared__ double rl[256];
  __shared__ double rs[256];
  const int t = threadIdx.x;
  double L = 0.0, S = 0.0;
  for (int i = t; i < 2048; i += 256) {
    double s = (double)simv[i];
    double dd = s - 0.5;
    L += dd * dd;
    S += s;
  }
  rl[t] = L; rs[t] = S;
  __syncthreads();
  for (int off = 128; off > 0; off >>= 1) {
    if (t < off) { rl[t] += rl[t + off]; rs[t] += rs[t + off]; }
    __syncthreads();
  }
  if (t == 0) {
    dout[2048] = (float)(rl[0] * (1.0 / 2048.0));
    dout[2049] = (float)(rs[0] * (1.0 / 2048.0));
  }
}

extern "C" void kernel_launch(void* const* d_in, const int* in_sizes, int n_in,
                              void* d_out, int out_size, void* d_ws, size_t ws_size,
                              hipStream_t stream) {
  const int* uid = (const int*)d_in[0];       // (2048,2) int32
  const float* xfeat = (const float*)d_in[1]; // (2048,256)
  const float* items = (const float*)d_in[2]; // (50000,128)
  const float* W = (const float*)d_in[3];     // (256,128)
  const float* bias = (const float*)d_in[4];  // (128,)
  const float* gamma = (const float*)d_in[5]; // (128,)
  const float* beta = (const float*)d_in[6];  // (128,)

  float* ws = (float*)d_ws;
  float* hraw = ws;                  // 262144
  float* hfin = ws + 262144;         // 262144
  float* meanv = ws + 524288;        // 128
  float* rsv = ws + 524416;          // 128
  float* V0 = ws + 524544;           // 2048
  float* pmax = ws + 526592;         // 2048*25 = 51200
  int* pidx = (int*)(ws + 577792);   // 51200
  float* simv = ws + 628992;         // 2048
  float* dout = (float*)d_out;       // 2050 floats

  hipLaunchKernelGGL(k_hraw, dim3(2048), dim3(128), 0, stream, xfeat, W, bias, hraw);
  hipLaunchKernelGGL(k_bnstats, dim3(128), dim3(256), 0, stream, hraw, meanv, rsv);
  hipLaunchKernelGGL(k_apply, dim3(1024), dim3(256), 0, stream, hraw, meanv, rsv, gamma, beta, hfin);
  hipLaunchKernelGGL(k_seed, dim3(512), dim3(256), 0, stream, hfin, items, V0);
  hipLaunchKernelGGL(k_scores, dim3(3200), dim3(256), 0, stream, hfin, items, V0, pmax, pidx);
  hipLaunchKernelGGL(k_final, dim3(2048), dim3(64), 0, stream, pmax, pidx, uid, items, dout, simv);
  hipLaunchKernelGGL(k_reduce, dim3(1), dim3(256), 0, stream, simv, dout);
}

// Round 7
// 1083.665 us; speedup vs baseline: 2.2877x; 2.2877x over previous
//
#include <hip/hip_runtime.h>
#include <math.h>

#define TINYF 1.17549435e-38f
#define NCHUNK 8
#define CHUNKJ 6250
#define QCAP 1024
#define GMAX 16.0f   // hard upper bound on gumbel (15.9424) + slack

// ---------------- threefry2x32, key = (0, 42), partitionable xor-combine ----
__device__ __forceinline__ unsigned rotl32(unsigned x, int r) {
  return (x << r) | (x >> (32 - r));
}

__device__ __forceinline__ unsigned tf2x32_xor(unsigned x0, unsigned x1) {
  const unsigned k0 = 0u, k1 = 42u, k2 = 0x1BD11BF0u;  // 0x1BD11BDA ^ 0 ^ 42
  x0 += k0; x1 += k1;
#define TFR(r) { x0 += x1; x1 = rotl32(x1, r); x1 ^= x0; }
  TFR(13) TFR(15) TFR(26) TFR(6)
  x0 += k1; x1 += k2 + 1u;
  TFR(17) TFR(29) TFR(16) TFR(24)
  x0 += k2; x1 += k0 + 2u;
  TFR(13) TFR(15) TFR(26) TFR(6)
  x0 += k0; x1 += k1 + 3u;
  TFR(17) TFR(29) TFR(16) TFR(24)
  x0 += k1; x1 += k2 + 4u;
  TFR(13) TFR(15) TFR(26) TFR(6)
  x0 += k2; x1 += k0 + 5u;
#undef TFR
  return x0 ^ x1;
}

__device__ __forceinline__ float gumbel_from_bits(unsigned bits) {
  float f = __uint_as_float((bits >> 9) | 0x3f800000u) - 1.0f;
  float u = fmaxf(f, TINYF);
  return -logf(-logf(u));
}

// order-preserving float->uint (monotone)
__device__ __forceinline__ unsigned ordf(float v) {
  unsigned b = __float_as_uint(v);
  return (b & 0x80000000u) ? ~b : (b | 0x80000000u);
}
__device__ __forceinline__ float unordf(unsigned u) {
  unsigned b = (u & 0x80000000u) ? (u & 0x7FFFFFFFu) : ~u;
  return __uint_as_float(b);
}

// ---------------- pack items -> k-quad-major: itemsP[kq][j][4] ----------------
// one-time 25.6MB relayout so k_scores a-loads are lane-contiguous dwordx4.
__global__ void k_pack(const float* __restrict__ items, float* __restrict__ itemsP) {
  const int linear = blockIdx.x * 256 + threadIdx.x;  // 32*50000 total
  const int kq = linear / 50000;
  const int j = linear - kq * 50000;
  float4 v = *(const float4*)(items + (size_t)j * 128 + kq * 4);
  *(float4*)(itemsP + ((size_t)kq * 50000 + j) * 4) = v;
}

// ---------------- h = x @ W + b (f64 accumulate) ----------------
__global__ void k_hraw(const float* __restrict__ x, const float* __restrict__ W,
                       const float* __restrict__ b, float* __restrict__ hraw) {
  __shared__ float sx[256];
  const int i = blockIdx.x;
  const int d = threadIdx.x;  // 128 threads
  sx[d] = x[i * 256 + d];
  sx[d + 128] = x[i * 256 + 128 + d];
  __syncthreads();
  double acc = 0.0;
  for (int k = 0; k < 256; ++k)
    acc = fma((double)sx[k], (double)W[k * 128 + d], acc);
  hraw[i * 128 + d] = (float)acc + b[d];
}

// ---------------- BN stats per column (f64) ----------------
__global__ void k_bnstats(const float* __restrict__ hraw,
                          float* __restrict__ meanv, float* __restrict__ rsv) {
  __shared__ double red[256];
  const int d = blockIdx.x;   // 128 blocks
  const int t = threadIdx.x;  // 256 threads
  double s = 0.0;
  for (int i = t; i < 2048; i += 256) s += (double)hraw[i * 128 + d];
  red[t] = s;
  __syncthreads();
  for (int off = 128; off > 0; off >>= 1) {
    if (t < off) red[t] += red[t + off];
    __syncthreads();
  }
  const float m = (float)(red[0] * (1.0 / 2048.0));
  __syncthreads();
  double v = 0.0;
  for (int i = t; i < 2048; i += 256) {
    float dd = __fsub_rn(hraw[i * 128 + d], m);
    v += (double)dd * (double)dd;
  }
  red[t] = v;
  __syncthreads();
  for (int off = 128; off > 0; off >>= 1) {
    if (t < off) red[t] += red[t + off];
    __syncthreads();
  }
  if (t == 0) {
    float var = (float)(red[0] * (1.0 / 2048.0));
    float vpe = __fadd_rn(var, 1e-5f);
    meanv[d] = m;
    rsv[d] = (float)(1.0 / sqrt((double)vpe));
  }
}

// ---------------- apply BN + leaky relu ----------------
__global__ void k_apply(const float* __restrict__ hraw,
                        const float* __restrict__ meanv, const float* __restrict__ rsv,
                        const float* __restrict__ gamma, const float* __restrict__ beta,
                        float* __restrict__ hfin) {
  const int idx = blockIdx.x * 256 + threadIdx.x;
  const int d = idx & 127;
  float h = hraw[idx];
  float hn = __fadd_rn(__fmul_rn(__fmul_rn(__fsub_rn(h, meanv[d]), rsv[d]), gamma[d]), beta[d]);
  hfin[idx] = (hn >= 0.0f) ? hn : __fmul_rn(0.01f, hn);
}

// ---------------- V0 seed: per-row achieved max over j in [0,1024) ----------
__global__ void k_seed(const float* __restrict__ hfin,
                       const float* __restrict__ items,
                       float* __restrict__ V0) {
  __shared__ float red[4][256];
  const int t = threadIdx.x;
  const int rbase = blockIdx.x * 4;
  float best[4] = {-INFINITY, -INFINITY, -INFINITY, -INFINITY};
  for (int q = 0; q < 4; ++q) {
    const int j = t + 256 * q;
    float acc[4] = {0.0f, 0.0f, 0.0f, 0.0f};
    const float* ap = items + (size_t)j * 128;
    for (int km = 0; km < 8; ++km) {
#pragma unroll
      for (int e = 0; e < 4; ++e) {
        float4 a4 = *(const float4*)(ap + km * 16 + 4 * e);
        float4 h4[4];
#pragma unroll
        for (int p = 0; p < 4; ++p)
          h4[p] = *(const float4*)(hfin + (rbase + p) * 128 + km * 16 + 4 * e);
#pragma unroll
        for (int p = 0; p < 4; ++p) {
          acc[p] = fmaf(h4[p].x, a4.x, acc[p]);
          acc[p] = fmaf(h4[p].y, a4.y, acc[p]);
          acc[p] = fmaf(h4[p].z, a4.z, acc[p]);
          acc[p] = fmaf(h4[p].w, a4.w, acc[p]);
        }
      }
    }
#pragma unroll
    for (int p = 0; p < 4; ++p) {
      unsigned l = (unsigned)(rbase + p) * 50000u + (unsigned)j;
      float g = gumbel_from_bits(tf2x32_xor(0u, l));
      best[p] = fmaxf(best[p], acc[p] + g);
    }
  }
#pragma unroll
  for (int p = 0; p < 4; ++p) red[p][t] = best[p];
  __syncthreads();
  for (int off = 128; off > 0; off >>= 1) {
    if (t < off) {
#pragma unroll
      for (int p = 0; p < 4; ++p) red[p][t] = fmaxf(red[p][t], red[p][t + off]);
    }
    __syncthreads();
  }
  if (t < 4) V0[rbase + t] = red[t][0];
}

// ---------------- fused scores + pruned gumbel + argmax ----------------
// grid 1024: c = bid&7 (== XCD -> 3.2MB packed chunk L2-resident), rt = bid>>3,
// rows r0..r0+15, j in [c*6250,(c+1)*6250), 7 j-tiles of 1024 (tail masked).
// Per thread: 4 j-cols x 16 rows; a-loads lane-contiguous dwordx4 (packed
// layout); h broadcast from LDS (b128, conflict-free, 16 FMAs per read).
// amdgpu_waves_per_eu(4,4): pin 4 waves/EU -> exactly 128-VGPR budget (the
// launch_bounds 2nd arg is only a MINIMUM -> allocator targeted 8 waves/EU
// and spilled acc to scratch in rounds 4-6).
__global__ __launch_bounds__(256)
__attribute__((amdgpu_waves_per_eu(4, 4)))
void k_scores(const float* __restrict__ hfin,
              const float* __restrict__ itemsP,
              const float* __restrict__ V0,
              float* __restrict__ pmax,
              int* __restrict__ pidx) {
  __shared__ __align__(16) float sh_h[2048];  // 16 rows x 128
  __shared__ unsigned q_key[QCAP];
  __shared__ float q_val[QCAP];
  __shared__ unsigned long long rowslot[16];
  __shared__ unsigned q_cnt;

  const int t = threadIdx.x;
  const int bid = blockIdx.x;
  const int rt = bid >> 3;
  const int c = bid & 7;
  const int r0 = rt * 16;
  const int jlo = c * CHUNKJ;
  const int jhi = jlo + CHUNKJ;

  *(float4*)(sh_h + t * 8) = *(const float4*)(hfin + r0 * 128 + t * 8);
  *(float4*)(sh_h + t * 8 + 4) = *(const float4*)(hfin + r0 * 128 + t * 8 + 4);
  if (t == 0) q_cnt = 0;
  if (t < 16) rowslot[t] = 0ull;
  __syncthreads();

  for (int jt = 0; jt < 7; ++jt) {
    const int jbase = jlo + jt * 1024 + t;
    int jj[4];
    bool vj[4];
    int jcl[4];
#pragma unroll
    for (int u = 0; u < 4; ++u) {
      jj[u] = jbase + 256 * u;
      vj[u] = jj[u] < jhi;
      jcl[u] = vj[u] ? jj[u] : (jhi - 1);
    }

    float acc[4][16];
#pragma unroll
    for (int u = 0; u < 4; ++u)
#pragma unroll
      for (int p = 0; p < 16; ++p) acc[u][p] = 0.0f;

    for (int kq = 0; kq < 32; ++kq) {
      float4 a4[4];
#pragma unroll
      for (int u = 0; u < 4; ++u)
        a4[u] = *(const float4*)(itemsP + ((size_t)kq * 50000 + (size_t)jcl[u]) * 4);

#pragma unroll
      for (int ph = 0; ph < 4; ++ph) {
        float4 h4[4];
#pragma unroll
        for (int r = 0; r < 4; ++r)
          h4[r] = *(const float4*)(sh_h + (ph * 4 + r) * 128 + kq * 4);
#pragma unroll
        for (int r = 0; r < 4; ++r) {
          const int p = ph * 4 + r;
#pragma unroll
          for (int u = 0; u < 4; ++u) {
            acc[u][p] = fmaf(h4[r].x, a4[u].x, acc[u][p]);
            acc[u][p] = fmaf(h4[r].y, a4[u].y, acc[u][p]);
            acc[u][p] = fmaf(h4[r].z, a4[u].z, acc[u][p]);
            acc[u][p] = fmaf(h4[r].w, a4[u].w, acc[u][p]);
          }
        }
      }
    }

    // push candidates: keep iff s + GMAX >= V0[row]
#pragma unroll
    for (int p = 0; p < 16; ++p) {
      const float vth = V0[r0 + p] - GMAX;  // uniform
#pragma unroll
      for (int u = 0; u < 4; ++u) {
        if (vj[u] && acc[u][p] >= vth) {
          unsigned slot = atomicAdd(&q_cnt, 1u);
          if (slot < QCAP) {
            q_key[slot] = ((unsigned)p << 16) | (unsigned)jj[u];
            q_val[slot] = acc[u][p];
          } else {  // overflow fallback: inline
            unsigned l = (unsigned)(r0 + p) * 50000u + (unsigned)jj[u];
            float v = acc[u][p] + gumbel_from_bits(tf2x32_xor(0u, l));
            unsigned long long pk =
                ((unsigned long long)ordf(v) << 32) | (0xFFFFFFFFu - (unsigned)jj[u]);
            atomicMax(&rowslot[p], pk);
          }
        }
      }
    }
  }

  __syncthreads();
  // dense flush: compute gumbel only for candidates
  const unsigned n = (q_cnt < QCAP) ? q_cnt : QCAP;
  for (unsigned i = t; i < n; i += 256) {
    unsigned key = q_key[i];
    unsigned p = key >> 16;
    unsigned j = key & 0xFFFFu;
    float s = q_val[i];
    unsigned l = (r0 + p) * 50000u + j;
    float v = s + gumbel_from_bits(tf2x32_xor(0u, l));
    unsigned long long pk = ((unsigned long long)ordf(v) << 32) | (0xFFFFFFFFu - j);
    atomicMax(&rowslot[p], pk);
  }
  __syncthreads();

  if (t < 16) {
    unsigned long long pk = rowslot[t];
    if (pk == 0ull) {
      pmax[(r0 + t) * NCHUNK + c] = -INFINITY;
      pidx[(r0 + t) * NCHUNK + c] = 0;
    } else {
      pmax[(r0 + t) * NCHUNK + c] = unordf((unsigned)(pk >> 32));
      pidx[(r0 + t) * NCHUNK + c] = (int)(0xFFFFFFFFu - (unsigned)pk);
    }
  }
}

// ---------------- chunk merge + cosine sim (one wave per row) ----------------
__global__ void k_final(const float* __restrict__ pmax, const int* __restrict__ pidx,
                        const int* __restrict__ uid, const float* __restrict__ items,
                        float* __restrict__ dout, float* __restrict__ simv) {
  const int r = blockIdx.x;
  const int lane = threadIdx.x;  // 64
  float bm = -INFINITY;
  int bi = 0;
  for (int c = 0; c < NCHUNK; ++c) {  // ascending c = ascending j
    float v = pmax[r * NCHUNK + c];
    int id = pidx[r * NCHUNK + c];
    if (v > bm || (v == bm && id < bi)) { bm = v; bi = id; }
  }
  if (lane == 0) dout[r] = (float)bi;

  const int orig = uid[r * 2 + 1];
  float o1 = items[(size_t)orig * 128 + lane];
  float o2 = items[(size_t)orig * 128 + 64 + lane];
  float p1 = items[(size_t)bi * 128 + lane];
  float p2 = items[(size_t)bi * 128 + 64 + lane];
  float d = o1 * p1 + o2 * p2;
  float s1 = o1 * o1 + o2 * o2;
  float s2 = p1 * p1 + p2 * p2;
  for (int off = 32; off > 0; off >>= 1) {
    d += __shfl_down(d, off);
    s1 += __shfl_down(s1, off);
    s2 += __shfl_down(s2, off);
  }
  if (lane == 0) {
    float n1 = fmaxf(sqrtf(s1), 1e-6f);
    float n2 = fmaxf(sqrtf(s2), 1e-6f);
    float sim = d / (n1 * n2);
    simv[r] = (sim + 1.0f) * 0.5f;
  }
}

// ---------------- final scalar reductions ----------------
__global__ void k_reduce(const float* __restrict__ simv, float* __restrict__ dout) {
  __shared__ double rl[256];
  __shared__ double rs[256];
  const int t = threadIdx.x;
  double L = 0.0, S = 0.0;
  for (int i = t; i < 2048; i += 256) {
    double s = (double)simv[i];
    double dd = s - 0.5;
    L += dd * dd;
    S += s;
  }
  rl[t] = L; rs[t] = S;
  __syncthreads();
  for (int off = 128; off > 0; off >>= 1) {
    if (t < off) { rl[t] += rl[t + off]; rs[t] += rs[t + off]; }
    __syncthreads();
  }
  if (t == 0) {
    dout[2048] = (float)(rl[0] * (1.0 / 2048.0));
    dout[2049] = (float)(rs[0] * (1.0 / 2048.0));
  }
}

extern "C" void kernel_launch(void* const* d_in, const int* in_sizes, int n_in,
                              void* d_out, int out_size, void* d_ws, size_t ws_size,
                              hipStream_t stream) {
  const int* uid = (const int*)d_in[0];       // (2048,2) int32
  const float* xfeat = (const float*)d_in[1]; // (2048,256)
  const float* items = (const float*)d_in[2]; // (50000,128)
  const float* W = (const float*)d_in[3];     // (256,128)
  const float* bias = (const float*)d_in[4];  // (128,)
  const float* gamma = (const float*)d_in[5]; // (128,)
  const float* beta = (const float*)d_in[6];  // (128,)

  float* ws = (float*)d_ws;
  float* hraw = ws;                  // [0, 262144)
  float* hfin = ws + 262144;         // [262144, 524288)
  float* meanv = ws + 524288;        // 128
  float* rsv = ws + 524416;          // 128
  float* V0 = ws + 524544;           // 2048
  float* pmax = ws + 526592;         // 2048*8 = 16384
  int* pidx = (int*)(ws + 542976);   // 16384
  float* simv = ws + 559360;         // 2048
  float* itemsP = ws + 561408;       // 6.4M floats (25.6MB), 16B-aligned
  float* dout = (float*)d_out;       // 2050 floats

  hipLaunchKernelGGL(k_pack, dim3(6250), dim3(256), 0, stream, items, itemsP);
  hipLaunchKernelGGL(k_hraw, dim3(2048), dim3(128), 0, stream, xfeat, W, bias, hraw);
  hipLaunchKernelGGL(k_bnstats, dim3(128), dim3(256), 0, stream, hraw, meanv, rsv);
  hipLaunchKernelGGL(k_apply, dim3(1024), dim3(256), 0, stream, hraw, meanv, rsv, gamma, beta, hfin);
  hipLaunchKernelGGL(k_seed, dim3(512), dim3(256), 0, stream, hfin, items, V0);
  hipLaunchKernelGGL(k_scores, dim3(1024), dim3(256), 0, stream, hfin, itemsP, V0, pmax, pidx);
  hipLaunchKernelGGL(k_final, dim3(2048), dim3(64), 0, stream, pmax, pidx, uid, items, dout, simv);
  hipLaunchKernelGGL(k_reduce, dim3(1), dim3(256), 0, stream, simv, dout);
}